// Round 6
// baseline (124.890 us; speedup 1.0000x reference)
//
#include <hip/hip_runtime.h>
#include <hip/hip_fp16.h>

// FixedPointLSTMCell on MI355X — R6: m201-faithful counted-vmcnt pipeline.
// 8 waves, 256 rows x 256 gate-major wrows, BK=64, 2 dbuf x 2 half-tiles per
// operand (128 KB LDS). Per phase: 12 ds_read_b128 + stage ONE half-tile
// (2 gload16/thread) into the slot freed last phase + barrier/lgkm/16 MFMA.
// vmcnt(4) ONLY at phases 4 and 8 (T4 counted, never 0 in steady state).
// 16-K-tile superloop covers both GEMMs (tiles 0-7: X·Wi^T, 8-15: H·Wh^T);
// X result rounded to Q8.8 and stashed as packed i16 pairs at the boundary.
// Exactness: all fake_quant'd operands are integers at scale 2^8; f16 MFMA on
// scaled ints is exact (fp32 accum < 2^24); elementwise replicates reference
// fp32 exactly (rintf = half-even, correctly-rounded /6, exact dyadic scales).

typedef _Float16 half8 __attribute__((ext_vector_type(8)));
typedef float f32x4 __attribute__((ext_vector_type(4)));

#define AS1 __attribute__((address_space(1)))
#define AS3 __attribute__((address_space(3)))

__device__ __forceinline__ void gload16(const void* g, void* l) {
  __builtin_amdgcn_global_load_lds((const AS1 void*)g, (AS3 void*)l, 16, 0, 0);
}

__device__ __forceinline__ float quant256(float v) {
  float q = rintf(v * 256.0f);
  return fminf(fmaxf(q, -32767.0f), 32767.0f);
}

// ---------------- prep: quantize inputs to integer-valued fp16 ----------------
__global__ __launch_bounds__(256) void prep_kernel(
    const float* __restrict__ x, const float* __restrict__ h,
    const float* __restrict__ Wi, const float* __restrict__ Wh,
    const float* __restrict__ bi, const float* __restrict__ bh,
    __half* __restrict__ xq, __half* __restrict__ hq,
    __half* __restrict__ wiq, __half* __restrict__ whq,
    float* __restrict__ biq, float* __restrict__ bhq) {
  const int i = blockIdx.x * 256 + threadIdx.x;  // 4 elems each
  {
    const float4 vx = ((const float4*)x)[i];
    const float4 vh = ((const float4*)h)[i];
    union { __half hh[4]; uint2 u; } ux, uh;
    ux.hh[0] = __half(quant256(vx.x)); ux.hh[1] = __half(quant256(vx.y));
    ux.hh[2] = __half(quant256(vx.z)); ux.hh[3] = __half(quant256(vx.w));
    uh.hh[0] = __half(quant256(vh.x)); uh.hh[1] = __half(quant256(vh.y));
    uh.hh[2] = __half(quant256(vh.z)); uh.hh[3] = __half(quant256(vh.w));
    ((uint2*)xq)[i] = ux.u;
    ((uint2*)hq)[i] = uh.u;
  }
  if (i < 262144) {  // weights: 2048*512/4
    const float4 vi4 = ((const float4*)Wi)[i];
    const float4 vh4 = ((const float4*)Wh)[i];
    union { __half hh[4]; uint2 u; } uwi, uwh;
    uwi.hh[0] = __half(quant256(vi4.x)); uwi.hh[1] = __half(quant256(vi4.y));
    uwi.hh[2] = __half(quant256(vi4.z)); uwi.hh[3] = __half(quant256(vi4.w));
    uwh.hh[0] = __half(quant256(vh4.x)); uwh.hh[1] = __half(quant256(vh4.y));
    uwh.hh[2] = __half(quant256(vh4.z)); uwh.hh[3] = __half(quant256(vh4.w));
    ((uint2*)wiq)[i] = uwi.u;
    ((uint2*)whq)[i] = uwh.u;
  }
  if (i < 512) {  // biases (scaled-int, as float)
    #pragma unroll
    for (int j = 0; j < 4; ++j) {
      biq[i * 4 + j] = quant256(bi[i * 4 + j]);
      bhq[i * 4 + j] = quant256(bh[i * 4 + j]);
    }
  }
}

// ---------------- pipelined gate-fused dual GEMM + LSTM cell ----------------
// Waves: wm = wid>>2 (128-row half), wn = wid&3 (16-col quarter).
// Wave output: 128 rows x 64 wrows; n-frag n == gate n (wrow = n*512 + col0 +
// wn*16 + l15) -> all 4 gates in-thread, fused epilogue.
// K-tile tau (0..15): src = tau<8 ? (xq,wiq) : (hq,whq); koff = (tau&7)*64;
// buffer = tau&1. A-half h = LDS rows {h*64..} ∪ {128+h*64..}; B-half h =
// wrows with bit5==h. Phase (mh,nh) reads A-half mh + B-half nh.
__global__ __launch_bounds__(512, 2) void lstm_gemm(
    const __half* __restrict__ xq, const __half* __restrict__ hq,
    const __half* __restrict__ wiq, const __half* __restrict__ whq,
    const float* __restrict__ biq, const float* __restrict__ bhq,
    const float* __restrict__ cprev,
    float* __restrict__ out_h, float* __restrict__ out_c) {
  __shared__ __align__(16) __half sA[2][256 * 64];  // 64 KB
  __shared__ __align__(16) __half sW[2][256 * 64];  // 64 KB

  const int tid = threadIdx.x;
  const int lane = tid & 63;
  const int wid = tid >> 6;      // 0..7
  const int wm = wid >> 2;       // 0..1
  const int wn = wid & 3;        // 0..3
  const int l15 = lane & 15;
  const int l4 = lane >> 4;
  const int s7 = l15 & 7;                                    // read swizzle key
  const int gswz = (((lane & 7) ^ ((lane >> 3) & 7)) << 3);  // stage swizzle

  // XCD-aware bijective swizzle (512 % 8 == 0)
  const int bid = blockIdx.x;
  const int lbid = (bid & 7) * 64 + (bid >> 3);
  const int tileM = lbid >> 3;   // 0..63
  const int tileN = lbid & 7;    // 0..7
  const int row0 = tileM * 256;
  const int col0 = tileN * 64;

  f32x4 acc[8][4];
  unsigned int stash[64];

  // preload biases (scaled ints) — issued before staging, drained by first vmcnt
  float bvi[4], bvh[4];
  #pragma unroll
  for (int n = 0; n < 4; ++n) {
    const int gwr = n * 512 + col0 + wn * 16 + l15;
    bvi[n] = biq[gwr];
    bvh[n] = bhq[gwr];
  }

  // ---- staging: one half-tile = 16 KB = 2 gload16/thread ----
  #define STAGE_A(h, db, tau)                                                 \
    if ((tau) < 16) {                                                         \
      const __half* src_ = ((tau) < 8) ? xq : hq;                             \
      const int ko_ = ((tau) & 7) * 64;                                       \
      _Pragma("unroll")                                                       \
      for (int l = 0; l < 2; ++l) {                                           \
        const int fr = (h) * 64 + wid * 8 + l * 128;  /* 8-aligned */         \
        const int goff = (row0 + fr + (lane >> 3)) * 512 + ko_ + gswz;        \
        gload16(src_ + goff, (char*)&sA[db][0] + fr * 128);                   \
      }                                                                       \
    }
  #define STAGE_B(h, db, tau)                                                 \
    if ((tau) < 16) {                                                         \
      const __half* src_ = ((tau) < 8) ? wiq : whq;                           \
      const int ko_ = ((tau) & 7) * 64;                                       \
      _Pragma("unroll")                                                       \
      for (int l = 0; l < 2; ++l) {                                           \
        const int c = l * 8 + wid;                                            \
        const int wf = (c & 3) * 8 + (h) * 32 + (c >> 2) * 64; /* 8-aligned */\
        const int w = wf + (lane >> 3);                                       \
        const int grow = ((w >> 4) & 3) * 512 + col0 + (w >> 6) * 16 + (w & 15); \
        const int goff = grow * 512 + ko_ + gswz;                             \
        gload16(src_ + goff, (char*)&sW[db][0] + wf * 128);                   \
      }                                                                       \
    }

  // counted waits: steady-state keeps the 2 newest half-tiles (4 loads) in
  // flight; last iteration (no new stagings) must drain fully.
  #define VMW                                                                 \
    { if (it < 7) { asm volatile("s_waitcnt vmcnt(4)" ::: "memory"); }        \
      else        { asm volatile("s_waitcnt vmcnt(0)" ::: "memory"); } }

  #define PHASE(bufc, mh, nh, STG, VM)                                        \
    {                                                                         \
      half8 av[2][4], bv[2][2];                                               \
      _Pragma("unroll")                                                       \
      for (int ks = 0; ks < 2; ++ks) {                                        \
        const int xo = (((ks * 4 + l4) ^ s7) << 3);                           \
        _Pragma("unroll")                                                     \
        for (int q = 0; q < 4; ++q)                                           \
          av[ks][q] = *(const half8*)&sA[bufc][(wm * 128 + (mh) * 64 + q * 16 + l15) * 64 + xo]; \
        _Pragma("unroll")                                                     \
        for (int n2 = 0; n2 < 2; ++n2)                                        \
          bv[ks][n2] = *(const half8*)&sW[bufc][(wn * 64 + (nh) * 32 + n2 * 16 + l15) * 64 + xo]; \
      }                                                                       \
      STG                                                                     \
      __builtin_amdgcn_s_barrier();                                           \
      asm volatile("s_waitcnt lgkmcnt(0)" ::: "memory");                      \
      __builtin_amdgcn_sched_barrier(0);                                      \
      __builtin_amdgcn_s_setprio(1);                                          \
      _Pragma("unroll")                                                       \
      for (int ks = 0; ks < 2; ++ks)                                          \
        _Pragma("unroll")                                                     \
        for (int q = 0; q < 4; ++q)                                           \
          _Pragma("unroll")                                                   \
          for (int n2 = 0; n2 < 2; ++n2)                                      \
            acc[(mh) * 4 + q][(nh) * 2 + n2] = __builtin_amdgcn_mfma_f32_16x16x32_f16( \
                av[ks][q], bv[ks][n2], acc[(mh) * 4 + q][(nh) * 2 + n2], 0, 0, 0); \
      __builtin_amdgcn_s_setprio(0);                                          \
      VM                                                                      \
      __builtin_amdgcn_s_barrier();                                           \
    }

  // zero acc
  {
    const f32x4 z = {0.f, 0.f, 0.f, 0.f};
    #pragma unroll
    for (int m = 0; m < 8; ++m)
      #pragma unroll
      for (int n = 0; n < 4; ++n) acc[m][n] = z;
  }

  // prologue: tile0 fully + tile1's first two halves; keep newest 2 halves
  // in flight (matches steady-state invariant at iteration entry)
  STAGE_A(0, 0, 0) STAGE_B(0, 0, 0) STAGE_A(1, 0, 0) STAGE_B(1, 0, 0)
  STAGE_A(0, 1, 1) STAGE_B(0, 1, 1)
  asm volatile("s_waitcnt vmcnt(4)" ::: "memory");
  __builtin_amdgcn_s_barrier();

  for (int it = 0; it < 8; ++it) {
    if (it == 4) {
      // X-GEMM done (tiles 0-7): round gi to Q8.8 ints (+bias), pack i16
      // pairs; then reset acc for the H-GEMM. Tile 8/9 loads fly meanwhile.
      #pragma unroll
      for (int n = 0; n < 4; ++n)
        #pragma unroll
        for (int m = 0; m < 8; ++m)
          #pragma unroll
          for (int jp = 0; jp < 2; ++jp) {
            float g0 = rintf(acc[m][n][jp * 2] * (1.0f / 256.0f) + bvi[n]);
            g0 = fminf(fmaxf(g0, -32767.f), 32767.f);
            float g1 = rintf(acc[m][n][jp * 2 + 1] * (1.0f / 256.0f) + bvi[n]);
            g1 = fminf(fmaxf(g1, -32767.f), 32767.f);
            stash[(m * 4 + n) * 2 + jp] =
                ((unsigned int)(int)g0 & 0xffffu) | ((unsigned int)(int)g1 << 16);
          }
      const f32x4 z = {0.f, 0.f, 0.f, 0.f};
      #pragma unroll
      for (int m = 0; m < 8; ++m)
        #pragma unroll
        for (int n = 0; n < 4; ++n) acc[m][n] = z;
    }
    const int ct = it * 2;
    // 8 phases; stage targets = slot freed one phase earlier (rotation
    // verified: read/write regions disjoint every phase)
    PHASE(0, 0, 0, STAGE_A(1, 1, ct + 1), )
    PHASE(0, 0, 1, STAGE_B(1, 1, ct + 1), )
    PHASE(0, 1, 0, STAGE_A(0, 0, ct + 2), )
    PHASE(0, 1, 1, STAGE_B(0, 0, ct + 2), VMW)
    PHASE(1, 0, 0, STAGE_A(1, 0, ct + 2), )
    PHASE(1, 0, 1, STAGE_B(1, 0, ct + 2), )
    PHASE(1, 1, 0, STAGE_A(0, 1, ct + 3), )
    PHASE(1, 1, 1, STAGE_B(0, 1, ct + 3), VMW)
  }
  #undef PHASE
  #undef STAGE_A
  #undef STAGE_B
  #undef VMW

  // ---- final epilogue: s = stash(gi) + round(gh); gates -> c, h ----
  #pragma unroll
  for (int m = 0; m < 8; ++m)
    #pragma unroll
    for (int j = 0; j < 4; ++j) {
      float s[4];
      #pragma unroll
      for (int g = 0; g < 4; ++g) {
        const unsigned int p = stash[(m * 4 + g) * 2 + (j >> 1)];
        const float gi = (float)((j & 1) ? (short)(p >> 16) : (short)(p & 0xffffu));
        float gh = rintf(acc[m][g][j] * (1.0f / 256.0f) + bvh[g]);
        gh = fminf(fmaxf(gh, -32767.f), 32767.f);
        s[g] = gi + gh;  // pre-activation * 256 (exact int)
      }
      float vi, vf, vo, gg;
      {
        float t0 = (s[0] * (1.0f / 256.0f)) / 6.0f + 0.5f;
        vi = rintf(fminf(fmaxf(t0, 0.0f), 1.0f) * 256.0f);
      }
      {
        float t1 = (s[1] * (1.0f / 256.0f)) / 6.0f + 0.5f;
        vf = rintf(fminf(fmaxf(t1, 0.0f), 1.0f) * 256.0f);
      }
      gg = fminf(fmaxf(s[2], -256.f), 256.f);  // hard_tanh + quant == clip
      {
        float t3 = (s[3] * (1.0f / 256.0f)) / 6.0f + 0.5f;
        vo = rintf(fminf(fmaxf(t3, 0.0f), 1.0f) * 256.0f);
      }
      const int R = row0 + wm * 128 + m * 16 + l4 * 4 + j;
      const int C = col0 + wn * 16 + l15;
      const float cpq = quant256(cprev[R * 512 + C]);
      const float cnum = vf * cpq + vi * gg;       // exact int, scale 2^16
      const float cval = cnum * (1.0f / 65536.0f);
      out_c[R * 512 + C] = cval;
      const float tt2 = fminf(fmaxf(cval, -1.0f), 1.0f);
      const float th = rintf(tt2 * 256.0f);
      out_h[R * 512 + C] = (vo * th) * (1.0f / 65536.0f);
    }
}

extern "C" void kernel_launch(void* const* d_in, const int* in_sizes, int n_in,
                              void* d_out, int out_size, void* d_ws, size_t ws_size,
                              hipStream_t stream) {
  const float* x      = (const float*)d_in[0];
  const float* h_prev = (const float*)d_in[1];
  const float* c_prev = (const float*)d_in[2];
  const float* W_ih   = (const float*)d_in[3];
  const float* b_ih   = (const float*)d_in[4];
  const float* W_hh   = (const float*)d_in[5];
  const float* b_hh   = (const float*)d_in[6];
  float* out = (float*)d_out;

  char* ws = (char*)d_ws;
  __half* xqp  = (__half*)(ws);
  __half* hqp  = (__half*)(ws + (16u << 20));
  __half* wiqp = (__half*)(ws + (32u << 20));
  __half* whqp = (__half*)(ws + (34u << 20));
  float*  biqp = (float*)(ws + (36u << 20));
  float*  bhqp = (float*)(ws + (36u << 20) + 8192);

  prep_kernel<<<8192, 256, 0, stream>>>(x, h_prev, W_ih, W_hh, b_ih, b_hh,
                                        xqp, hqp, wiqp, whqp, biqp, bhqp);

  lstm_gemm<<<512, 512, 0, stream>>>(xqp, hqp, wiqp, whqp, biqp, bhqp,
                                     c_prev, out, out + 8388608);
}